// Round 12
// baseline (18.349 us; speedup 1.0000x reference)
//
#include <hip/hip_runtime.h>
#include <math.h>

#define NQ 10

typedef float v2f __attribute__((ext_vector_type(2)));

static __device__ __forceinline__ v2f mk2(float a, float b) { v2f r; r.x = a; r.y = b; return r; }
static __device__ __forceinline__ v2f sp2(float a)          { v2f r; r.x = a; r.y = a; return r; }
static __device__ __forceinline__ v2f pkfma(v2f a, v2f b, v2f c) { return __builtin_elementwise_fma(a, b, c); }

// xor-mask lane exchange. Masks 1,2,4,8: DPP (VALU). 16: ds_swizzle. 32: bpermute.
template<int MSK>
static __device__ __forceinline__ float lxor(float v) {
    if constexpr (MSK == 1) {        // quad_perm [1,0,3,2]
        const int s = __float_as_int(v);
        return __int_as_float(__builtin_amdgcn_update_dpp(s, s, 0xB1, 0xF, 0xF, false));
    } else if constexpr (MSK == 2) { // quad_perm [2,3,0,1]
        const int s = __float_as_int(v);
        return __int_as_float(__builtin_amdgcn_update_dpp(s, s, 0x4E, 0xF, 0xF, false));
    } else if constexpr (MSK == 4) {
        // banks 0,2 (bit2=0) need lane+4 -> row_shl:4 ; banks 1,3 (bit2=1) need lane-4 -> row_shr:4
        const int s = __float_as_int(v);
        int t = __builtin_amdgcn_update_dpp(s, s, 0x104, 0xF, 0x5, false);
        t     = __builtin_amdgcn_update_dpp(t, s, 0x114, 0xF, 0xA, false);
        return __int_as_float(t);
    } else if constexpr (MSK == 8) { // row_ror:8 == xor8 within a 16-lane row
        const int s = __float_as_int(v);
        return __int_as_float(__builtin_amdgcn_update_dpp(s, s, 0x128, 0xF, 0xF, false));
    } else if constexpr (MSK == 16) {
        return __int_as_float(__builtin_amdgcn_ds_swizzle(__float_as_int(v), 0x401F));
    } else {
        return __shfl_xor(v, 32, 64);
    }
}
template<int MSK>
static __device__ __forceinline__ v2f lxor2(v2f v) { return mk2(lxor<MSK>(v.x), lxor<MSK>(v.y)); }

// Dual-destination permlane swaps (gfx950, VALU pipe, both operands modified).
#define PLS32(a, b) asm("v_permlane32_swap_b32 %0, %1" : "+v"(a), "+v"(b))
#define PLS16(a, b) asm("v_permlane16_swap_b32 %0, %1" : "+v"(a), "+v"(b))

// TWO batch elements per WAVE (ILP=2; 8 elements per 256-thread block).
// k = m*64+lane, m = 2p+e. Reduced circuit per element:
//   P0 (weights-only, shared) -> D1 -> RY1 -> D2 -> RY2 -> D3 -> RY3 -> |.|^2
// Gate coefficients shared across the two elements; only D and epilogue duplicate.
__global__ __launch_bounds__(256, 1) void qlayer_kernel(
    const float* __restrict__ x,    // [B,10]
    const float* __restrict__ w1,   // [3,1,10,3]
    const float* __restrict__ w2,   // [1,10,3]
    float* __restrict__ out)        // [B,10]
{
    __shared__ float ry[4 * 20];   // (c,s)(theta/2) per layer L=0..3, wire j=0..9
    __shared__ float au[3 * 10];   // omega_L[j] + phi_{L+1}[j], L=0..2

    const int t    = threadIdx.x;
    const int lane = t & 63;
    const int w    = t >> 6;
    const int b0   = (blockIdx.x << 3) + (w << 1);   // this wave's two elements

    if (t < 40) {
        const int L = t / 10, j = t - L * 10;
        const float th = (L < 3) ? w1[L * 30 + j * 3 + 1] : w2[j * 3 + 1];
        float c, s;
        __sincosf(0.5f * th, &s, &c);
        ry[L * 20 + j * 2 + 0] = c;
        ry[L * 20 + j * 2 + 1] = s;
    } else if (t >= 64 && t < 94) {
        const int i = t - 64, L = i / 10, j = i - L * 10;
        au[i] = w1[L * 30 + j * 3 + 2] + ((L < 2) ? w1[(L + 1) * 30 + j * 3] : w2[j * 3]);
    }

    // two x rows = 20 consecutive floats; b0 even -> byte offset 80*(b0/2), 16B-aligned
    float xv[2][NQ];
    {
        const float4* xp = (const float4*)(x + b0 * NQ);
        const float4 q0 = xp[0], q1 = xp[1], q2 = xp[2], q3 = xp[3], q4 = xp[4];
        xv[0][0] = q0.x; xv[0][1] = q0.y; xv[0][2] = q0.z; xv[0][3] = q0.w;
        xv[0][4] = q1.x; xv[0][5] = q1.y; xv[0][6] = q1.z; xv[0][7] = q1.w;
        xv[0][8] = q2.x; xv[0][9] = q2.y;
        xv[1][0] = q2.z; xv[1][1] = q2.w; xv[1][2] = q3.x; xv[1][3] = q3.y;
        xv[1][4] = q3.z; xv[1][5] = q3.w; xv[1][6] = q4.x; xv[1][7] = q4.y;
        xv[1][8] = q4.z; xv[1][9] = q4.w;
    }

    // sign masks (lane bits 0..3; bit set -> +s, clear -> -s)
    int msk[4];
#pragma unroll
    for (int p = 0; p < 4; ++p) msk[p] = ((lane >> p) & 1) ? 0 : 0x80000000;

    // CZ-ring sign per m (k = m<<6 | lane) — lane-only, shared by both elements
    float czm[16];
#pragma unroll
    for (int m = 0; m < 16; ++m) {
        const int k  = (m << 6) | lane;
        const int kr = ((k << 1) | (k >> 9)) & 1023;
        czm[m] = (__popc(k & kr) & 1) ? -1.f : 1.f;
    }

    __syncthreads();   // tables ready (only block barrier)

    v2f dr[2][8], di[2][8];
#define BUILD_D(IDX, E)                                                                \
    {                                                                                  \
        float A[NQ];                                                                   \
        _Pragma("unroll")                                                              \
        for (int j = 0; j < NQ; ++j) A[j] = au[(IDX) * 10 + j] + xv[E][j];             \
        float SA = 0.f;                                                                \
        _Pragma("unroll")                                                              \
        for (int j = 0; j < NQ; ++j) SA += A[j];                                       \
        float Tl = 0.f;                                                                \
        _Pragma("unroll")                                                              \
        for (int p = 0; p < 6; ++p) Tl += ((lane >> p) & 1) ? A[9 - p] : 0.f;          \
        const float base = -0.5f * SA + Tl;                                            \
        float fr[4], fi[4];                                                            \
        _Pragma("unroll")                                                              \
        for (int q = 0; q < 4; ++q) __sincosf(A[3 - q], &fi[q], &fr[q]);               \
        float dmr[16], dmi[16];                                                        \
        __sincosf(base, &dmi[0], &dmr[0]);                                             \
        _Pragma("unroll")                                                              \
        for (int m = 1; m < 16; ++m) {                                                 \
            const int q  = (m & 1) ? 0 : (m & 2) ? 1 : (m & 4) ? 2 : 3;                \
            const int pm = m & (m - 1);                                                \
            dmr[m] = dmr[pm] * fr[q] - dmi[pm] * fi[q];                                \
            dmi[m] = dmr[pm] * fi[q] + dmi[pm] * fr[q];                                \
        }                                                                              \
        _Pragma("unroll")                                                              \
        for (int p = 0; p < 8; ++p) {                                                  \
            dr[E][p] = mk2(dmr[2*p] * czm[2*p], dmr[2*p+1] * czm[2*p+1]);              \
            di[E][p] = mk2(dmi[2*p] * czm[2*p], dmi[2*p+1] * czm[2*p+1]);              \
        }                                                                              \
    }

    // ---- initial product state RY0|0..0>: weights-only -> shared across elements ----
    float Plo = 1.f;
#pragma unroll
    for (int p = 0; p < 6; ++p) {       // lane bit p <-> wire 9-p
        const float cc = ry[(9 - p) * 2], ss = ry[(9 - p) * 2 + 1];
        Plo *= ((lane >> p) & 1) ? ss : cc;
    }
    float Pm[16];
    {
        const float c0 = ry[0], s0 = ry[1], c1 = ry[2], s1 = ry[3];
        const float c2 = ry[4], s2 = ry[5], c3 = ry[6], s3 = ry[7];
        float P2[2] = {c3, s3};          // m bit0 = wire 3
        float P4[4], P8[8];
#pragma unroll
        for (int m = 0; m < 4; ++m)  P4[m] = ((m >> 1) ? s2 : c2) * P2[m & 1];
#pragma unroll
        for (int m = 0; m < 8; ++m)  P8[m] = ((m >> 2) ? s1 : c1) * P4[m & 3];
#pragma unroll
        for (int m = 0; m < 16; ++m) Pm[m] = ((m >> 3) ? s0 : c0) * P8[m & 7];
    }

    BUILD_D(0, 0)
    BUILD_D(0, 1)
    v2f sr[2][8], si[2][8];
#pragma unroll
    for (int p = 0; p < 8; ++p) {
        const v2f pv = sp2(Plo) * mk2(Pm[2 * p], Pm[2 * p + 1]);
        sr[0][p] = pv * dr[0][p];  si[0][p] = pv * di[0][p];
        sr[1][p] = pv * dr[1][p];  si[1][p] = pv * di[1][p];
    }

// single-DPP lane wires (masks 1,2,8): scalar form, DPP fusable into consumer src0
#define RY_LANE_S(J, MSK)                                                       \
    {                                                                           \
        const float c = rl[(J) * 2], s = rl[(J) * 2 + 1];                       \
        const float ssg = __int_as_float(__float_as_int(s) ^ msk[9 - (J)]);     \
        _Pragma("unroll")                                                       \
        for (int e = 0; e < 2; ++e) {                                           \
            _Pragma("unroll")                                                   \
            for (int p = 0; p < 8; ++p) {                                       \
                const float qx  = lxor<MSK>(sr[e][p].x);                        \
                const float qy  = lxor<MSK>(sr[e][p].y);                        \
                const float rx  = lxor<MSK>(si[e][p].x);                        \
                const float ryv = lxor<MSK>(si[e][p].y);                        \
                sr[e][p].x = fmaf(qx,  ssg, c * sr[e][p].x);                    \
                sr[e][p].y = fmaf(qy,  ssg, c * sr[e][p].y);                    \
                si[e][p].x = fmaf(rx,  ssg, c * si[e][p].x);                    \
                si[e][p].y = fmaf(ryv, ssg, c * si[e][p].y);                    \
            }                                                                   \
        }                                                                       \
    }

// two-mov DPP wire (mask 4): packed form
#define RY_LANE_V(J, MSK)                                                       \
    {                                                                           \
        const float c = rl[(J) * 2], s = rl[(J) * 2 + 1];                       \
        const float ssg = __int_as_float(__float_as_int(s) ^ msk[9 - (J)]);     \
        const v2f C = sp2(c), S = sp2(ssg);                                     \
        _Pragma("unroll")                                                       \
        for (int e = 0; e < 2; ++e) {                                           \
            _Pragma("unroll")                                                   \
            for (int p = 0; p < 8; ++p) {                                       \
                const v2f qr = lxor2<MSK>(sr[e][p]);                            \
                const v2f qi = lxor2<MSK>(si[e][p]);                            \
                sr[e][p] = pkfma(C, sr[e][p], S * qr);                          \
                si[e][p] = pkfma(C, si[e][p], S * qi);                          \
            }                                                                   \
        }                                                                       \
    }

// permlane pair wires (masks 32,16): swap -> uniform-sign gate -> swap back
#define RY_PLPAIR(J, PLS)                                                       \
    {                                                                           \
        const float c = rl[(J) * 2], s = rl[(J) * 2 + 1];                       \
        const v2f C = sp2(c), S = sp2(s), nS = sp2(-s);                         \
        _Pragma("unroll")                                                       \
        for (int e = 0; e < 2; ++e) {                                           \
            _Pragma("unroll")                                                   \
            for (int p = 0; p < 8; ++p) {                                       \
                float ux = sr[e][p].x, uy = sr[e][p].y;                         \
                float vx = si[e][p].x, vy = si[e][p].y;                         \
                PLS(ux, vx); PLS(uy, vy);                                       \
                const v2f u = mk2(ux, uy), v = mk2(vx, vy);                     \
                const v2f t1 = pkfma(C, u, nS * v);                             \
                const v2f t2 = pkfma(C, v,  S * u);                             \
                float ax = t1.x, ay = t1.y, bx = t2.x, by = t2.y;               \
                PLS(ax, bx); PLS(ay, by);                                       \
                sr[e][p] = mk2(ax, ay); si[e][p] = mk2(bx, by);                 \
            }                                                                   \
        }                                                                       \
    }

#pragma unroll 1
    for (int L = 1; L <= 3; ++L) {
        const float* rl = ry + L * 20;

        RY_PLPAIR(4, PLS32)   // lane bit 5
        RY_PLPAIR(5, PLS16)   // lane bit 4
        RY_LANE_S(6, 8)
        RY_LANE_V(7, 4)
        RY_LANE_S(8, 2)
        RY_LANE_S(9, 1)

        // p-wires j=0,1,2 (p bits 2,1,0): real pair rotations
#pragma unroll
        for (int j = 0; j < 3; ++j) {
            const int pb = 4 >> j;
            const float c = rl[j * 2], s = rl[j * 2 + 1];
            const v2f C = sp2(c), S = sp2(s), nS = sp2(-s);
#pragma unroll
            for (int e = 0; e < 2; ++e) {
#pragma unroll
                for (int p0 = 0; p0 < 8; ++p0) {
                    if (p0 & pb) continue;
                    const int p1 = p0 | pb;
                    const v2f a0r = sr[e][p0], a1r = sr[e][p1];
                    const v2f a0i = si[e][p0], a1i = si[e][p1];
                    sr[e][p0] = pkfma(C, a0r, nS * a1r);
                    sr[e][p1] = pkfma(C, a1r,  S * a0r);
                    si[e][p0] = pkfma(C, a0i, nS * a1i);
                    si[e][p1] = pkfma(C, a1i,  S * a0i);
                }
            }
        }

        // e-wire j=3 (intra-v2f): new.x = c*x - s*y ; new.y = s*x + c*y
        {
            const float c = rl[6], s = rl[7];
            const v2f C = sp2(c), Sw = mk2(-s, s);
#pragma unroll
            for (int e = 0; e < 2; ++e) {
#pragma unroll
                for (int p = 0; p < 8; ++p) {
                    const v2f swr = mk2(sr[e][p].y, sr[e][p].x);
                    const v2f swi = mk2(si[e][p].y, si[e][p].x);
                    sr[e][p] = pkfma(C, sr[e][p], Sw * swr);
                    si[e][p] = pkfma(C, si[e][p], Sw * swi);
                }
            }
        }

        // fused diagonal D_{L+1}
        if (L < 3) {
            BUILD_D(L, 0)
            BUILD_D(L, 1)
#pragma unroll
            for (int e = 0; e < 2; ++e) {
#pragma unroll
                for (int p = 0; p < 8; ++p) {
                    const v2f tr = pkfma(sr[e][p], dr[e][p], -(si[e][p] * di[e][p]));
                    si[e][p] = pkfma(sr[e][p], di[e][p], si[e][p] * dr[e][p]);
                    sr[e][p] = tr;
                }
            }
        }
    }
#undef RY_LANE_S
#undef RY_LANE_V
#undef RY_PLPAIR
#undef BUILD_D

    // ---- <Z_j> per element ----
#pragma unroll
    for (int e = 0; e < 2; ++e) {
        float pe[8], po[8];
#pragma unroll
        for (int p = 0; p < 8; ++p) {
            const v2f pk = pkfma(sr[e][p], sr[e][p], si[e][p] * si[e][p]);
            pe[p] = pk.x + pk.y;
            po[p] = pk.x - pk.y;
        }
        float tot = 0.f, t0 = 0.f, t1 = 0.f, t2 = 0.f, t3 = 0.f;
#pragma unroll
        for (int p = 0; p < 8; ++p) {
            tot += pe[p];
            t0  += (p & 4) ? -pe[p] : pe[p];   // wire 0 (m bit 3)
            t1  += (p & 2) ? -pe[p] : pe[p];   // wire 1 (m bit 2)
            t2  += (p & 1) ? -pe[p] : pe[p];   // wire 2 (m bit 1)
            t3  += po[p];                      // wire 3 (m bit 0)
        }
        v2f u01 = mk2(t0, t1), u23 = mk2(t2, t3);
        u01 += lxor2<1>(u01);  u23 += lxor2<1>(u23);
        u01 += lxor2<2>(u01);  u23 += lxor2<2>(u23);
        u01 += lxor2<4>(u01);  u23 += lxor2<4>(u23);
        u01 += lxor2<8>(u01);  u23 += lxor2<8>(u23);
        u01 += lxor2<16>(u01); u23 += lxor2<16>(u23);
        u01 += lxor2<32>(u01); u23 += lxor2<32>(u23);

        float Sa = tot, T, D0, D1, D2, D3, D4, D5;
        T = lxor<1>(Sa);  D0 = Sa - T; Sa += T;
        T = lxor<2>(Sa);  D1 = Sa - T; Sa += T;
        T = lxor<4>(Sa);  D2 = Sa - T; Sa += T;
        T = lxor<8>(Sa);  D3 = Sa - T; Sa += T;
        T = lxor<16>(Sa); D4 = Sa - T; Sa += T;
        T = lxor<32>(Sa); D5 = Sa - T;
        D0 += lxor<2>(D0); D0 += lxor<4>(D0); D0 += lxor<8>(D0); D0 += lxor<16>(D0); D0 += lxor<32>(D0);
        D1 += lxor<4>(D1); D1 += lxor<8>(D1); D1 += lxor<16>(D1); D1 += lxor<32>(D1);
        D2 += lxor<8>(D2); D2 += lxor<16>(D2); D2 += lxor<32>(D2);
        D3 += lxor<16>(D3); D3 += lxor<32>(D3);
        D4 += lxor<32>(D4);

        if (lane == 0) {
            float* o = out + (b0 + e) * NQ;
            o[0] = u01.x; o[1] = u01.y; o[2] = u23.x; o[3] = u23.y;
            o[4] = D5;    o[5] = D4;    o[6] = D3;    o[7] = D2;    o[8] = D1;    o[9] = D0;
        }
    }
}

extern "C" void kernel_launch(void* const* d_in, const int* in_sizes, int n_in,
                              void* d_out, int out_size, void* d_ws, size_t ws_size,
                              hipStream_t stream) {
    const float* x  = (const float*)d_in[0];   // [B,10] f32
    const float* w1 = (const float*)d_in[1];   // [3,1,10,3] f32
    const float* w2 = (const float*)d_in[2];   // [1,10,3] f32
    float* out = (float*)d_out;                // [B,10] f32
    const int B = in_sizes[0] / NQ;            // 2048
    qlayer_kernel<<<B / 8, 256, 0, stream>>>(x, w1, w2, out);  // 2 elements per wave
}

// Round 13
// 17.963 us; speedup vs baseline: 1.0215x; 1.0215x over previous
//
#include <hip/hip_runtime.h>
#include <math.h>

#define NQ 10

typedef float v2f __attribute__((ext_vector_type(2)));

static __device__ __forceinline__ v2f mk2(float a, float b) { v2f r; r.x = a; r.y = b; return r; }
static __device__ __forceinline__ v2f sp2(float a)          { v2f r; r.x = a; r.y = a; return r; }
static __device__ __forceinline__ v2f pkfma(v2f a, v2f b, v2f c) { return __builtin_elementwise_fma(a, b, c); }

// xor-mask lane exchange. Masks 1,2,4,8: DPP (VALU). 16: ds_swizzle. 32: bpermute.
template<int MSK>
static __device__ __forceinline__ float lxor(float v) {
    if constexpr (MSK == 1) {        // quad_perm [1,0,3,2]
        const int s = __float_as_int(v);
        return __int_as_float(__builtin_amdgcn_update_dpp(s, s, 0xB1, 0xF, 0xF, false));
    } else if constexpr (MSK == 2) { // quad_perm [2,3,0,1]
        const int s = __float_as_int(v);
        return __int_as_float(__builtin_amdgcn_update_dpp(s, s, 0x4E, 0xF, 0xF, false));
    } else if constexpr (MSK == 4) {
        // banks 0,2 (bit2=0) need lane+4 -> row_shl:4 ; banks 1,3 (bit2=1) need lane-4 -> row_shr:4
        const int s = __float_as_int(v);
        int t = __builtin_amdgcn_update_dpp(s, s, 0x104, 0xF, 0x5, false);
        t     = __builtin_amdgcn_update_dpp(t, s, 0x114, 0xF, 0xA, false);
        return __int_as_float(t);
    } else if constexpr (MSK == 8) { // row_ror:8 == xor8 within a 16-lane row
        const int s = __float_as_int(v);
        return __int_as_float(__builtin_amdgcn_update_dpp(s, s, 0x128, 0xF, 0xF, false));
    } else if constexpr (MSK == 16) {
        return __int_as_float(__builtin_amdgcn_ds_swizzle(__float_as_int(v), 0x401F));
    } else {
        return __shfl_xor(v, 32, 64);
    }
}
template<int MSK>
static __device__ __forceinline__ v2f lxor2(v2f v) { return mk2(lxor<MSK>(v.x), lxor<MSK>(v.y)); }

// Dual-destination permlane swaps (gfx950, VALU pipe, both operands modified).
#define PLS32(a, b) asm("v_permlane32_swap_b32 %0, %1" : "+v"(a), "+v"(b))
#define PLS16(a, b) asm("v_permlane16_swap_b32 %0, %1" : "+v"(a), "+v"(b))

// ONE WAVE PER BLOCK (64 threads), one batch element per wave. k = m*64+lane, m = 2p+e.
// Reduced circuit: P0 (real product state) -> D1 -> RY1 -> D2 -> RY2 -> D3 -> RY3 -> |.|^2.
// vs R10: no __syncthreads anywhere (single-wave block), per-wave tables, 2048
// independent blocks -> waves on a SIMD drift out of lockstep instead of colliding
// on the same pipe in the same cycles.
__global__ __launch_bounds__(64, 2) void qlayer_kernel(
    const float* __restrict__ x,    // [B,10]
    const float* __restrict__ w1,   // [3,1,10,3]
    const float* __restrict__ w2,   // [1,10,3]
    float* __restrict__ out)        // [B,10]
{
    __shared__ float ry[4 * 20];   // (c,s)(theta/2) per layer L=0..3, wire j=0..9
    __shared__ float au[3 * 10];   // omega_L[j] + phi_{L+1}[j], L=0..2

    const int t    = threadIdx.x;  // == lane
    const int lane = t;
    const int b    = blockIdx.x;

    // per-wave tables (lanes 0..39); same-wave LDS visibility needs only lgkmcnt,
    // which the compiler emits — no barrier in the whole kernel.
    if (t < 40) {
        const int L = t / 10, j = t - L * 10;
        const float th = (L < 3) ? w1[L * 30 + j * 3 + 1] : w2[j * 3 + 1];
        float c, s;
        __sincosf(0.5f * th, &s, &c);
        ry[L * 20 + j * 2 + 0] = c;
        ry[L * 20 + j * 2 + 1] = s;
        if (t < 30) {
            au[t] = w1[L * 30 + j * 3 + 2] + ((L < 2) ? w1[(L + 1) * 30 + j * 3] : w2[j * 3]);
        }
    }

    float xv[NQ];
#pragma unroll
    for (int j = 0; j < NQ; ++j) xv[j] = x[b * NQ + j];

    // sign masks (lane bits 0..3; bit set -> +s, clear -> -s)
    int msk[4];
#pragma unroll
    for (int p = 0; p < 4; ++p) msk[p] = ((lane >> p) & 1) ? 0 : 0x80000000;

    // CZ-ring sign per m (k = m<<6 | lane)
    float czm[16];
#pragma unroll
    for (int m = 0; m < 16; ++m) {
        const int k  = (m << 6) | lane;
        const int kr = ((k << 1) | (k >> 9)) & 1023;
        czm[m] = (__popc(k & kr) & 1) ? -1.f : 1.f;
    }

    // D build: d = cz * exp(i*ang(k)), ang(k) = -SA/2 + sum_{bits set} A[wire]
    v2f dr[8], di[8];
#define BUILD_D(IDX)                                                                   \
    {                                                                                  \
        float A[NQ];                                                                   \
        _Pragma("unroll")                                                              \
        for (int j = 0; j < NQ; ++j) A[j] = au[(IDX) * 10 + j] + xv[j];                \
        float SA = 0.f;                                                                \
        _Pragma("unroll")                                                              \
        for (int j = 0; j < NQ; ++j) SA += A[j];                                       \
        float Tl = 0.f;                                                                \
        _Pragma("unroll")                                                              \
        for (int p = 0; p < 6; ++p) Tl += ((lane >> p) & 1) ? A[9 - p] : 0.f;          \
        const float base = -0.5f * SA + Tl;                                            \
        float fr[4], fi[4];                                                            \
        _Pragma("unroll")                                                              \
        for (int q = 0; q < 4; ++q) __sincosf(A[3 - q], &fi[q], &fr[q]);               \
        float dmr[16], dmi[16];                                                        \
        __sincosf(base, &dmi[0], &dmr[0]);                                             \
        _Pragma("unroll")                                                              \
        for (int m = 1; m < 16; ++m) {                                                 \
            const int q  = (m & 1) ? 0 : (m & 2) ? 1 : (m & 4) ? 2 : 3;                \
            const int pm = m & (m - 1);                                                \
            dmr[m] = dmr[pm] * fr[q] - dmi[pm] * fi[q];                                \
            dmi[m] = dmr[pm] * fi[q] + dmi[pm] * fr[q];                                \
        }                                                                              \
        _Pragma("unroll")                                                              \
        for (int p = 0; p < 8; ++p) {                                                  \
            dr[p] = mk2(dmr[2*p] * czm[2*p], dmr[2*p+1] * czm[2*p+1]);                 \
            di[p] = mk2(dmi[2*p] * czm[2*p], dmi[2*p+1] * czm[2*p+1]);                 \
        }                                                                              \
    }

    // ---- initial product state: RY-block 0 applied to |0..0> ----
    float Plo = 1.f;
#pragma unroll
    for (int p = 0; p < 6; ++p) {       // lane bit p <-> wire 9-p
        const float cc = ry[(9 - p) * 2], ss = ry[(9 - p) * 2 + 1];
        Plo *= ((lane >> p) & 1) ? ss : cc;
    }
    float Pm[16];
    {
        const float c0 = ry[0], s0 = ry[1], c1 = ry[2], s1 = ry[3];
        const float c2 = ry[4], s2 = ry[5], c3 = ry[6], s3 = ry[7];
        float P2[2] = {c3, s3};          // m bit0 = wire 3
        float P4[4], P8[8];
#pragma unroll
        for (int m = 0; m < 4; ++m)  P4[m] = ((m >> 1) ? s2 : c2) * P2[m & 1];
#pragma unroll
        for (int m = 0; m < 8; ++m)  P8[m] = ((m >> 2) ? s1 : c1) * P4[m & 3];
#pragma unroll
        for (int m = 0; m < 16; ++m) Pm[m] = ((m >> 3) ? s0 : c0) * P8[m & 7];
    }

    BUILD_D(0)
    v2f sr[8], si[8];
#pragma unroll
    for (int p = 0; p < 8; ++p) {
        const v2f pv = sp2(Plo) * mk2(Pm[2 * p], Pm[2 * p + 1]);
        sr[p] = pv * dr[p];
        si[p] = pv * di[p];
    }

// single-DPP lane wires (masks 1,2,8): scalar form, DPP fusable into consumer src0
#define RY_LANE_S(J, MSK)                                                       \
    {                                                                           \
        const float c = rl[(J) * 2], s = rl[(J) * 2 + 1];                       \
        const float ssg = __int_as_float(__float_as_int(s) ^ msk[9 - (J)]);     \
        _Pragma("unroll")                                                       \
        for (int p = 0; p < 8; ++p) {                                           \
            const float qx  = lxor<MSK>(sr[p].x);                               \
            const float qy  = lxor<MSK>(sr[p].y);                               \
            const float rx  = lxor<MSK>(si[p].x);                               \
            const float ryv = lxor<MSK>(si[p].y);                               \
            sr[p].x = fmaf(qx,  ssg, c * sr[p].x);                              \
            sr[p].y = fmaf(qy,  ssg, c * sr[p].y);                              \
            si[p].x = fmaf(rx,  ssg, c * si[p].x);                              \
            si[p].y = fmaf(ryv, ssg, c * si[p].y);                              \
        }                                                                       \
    }

// two-mov DPP wire (mask 4): packed form
#define RY_LANE_V(J, MSK)                                                       \
    {                                                                           \
        const float c = rl[(J) * 2], s = rl[(J) * 2 + 1];                       \
        const float ssg = __int_as_float(__float_as_int(s) ^ msk[9 - (J)]);     \
        const v2f C = sp2(c), S = sp2(ssg);                                     \
        _Pragma("unroll")                                                       \
        for (int p = 0; p < 8; ++p) {                                           \
            const v2f qr = lxor2<MSK>(sr[p]);                                   \
            const v2f qi = lxor2<MSK>(si[p]);                                   \
            sr[p] = pkfma(C, sr[p], S * qr);                                    \
            si[p] = pkfma(C, si[p], S * qi);                                    \
        }                                                                       \
    }

// permlane pair wires (masks 32,16): swap -> uniform-sign gate -> swap back
#define RY_PLPAIR(J, PLS)                                                       \
    {                                                                           \
        const float c = rl[(J) * 2], s = rl[(J) * 2 + 1];                       \
        const v2f C = sp2(c), S = sp2(s), nS = sp2(-s);                         \
        _Pragma("unroll")                                                       \
        for (int p = 0; p < 8; ++p) {                                           \
            float ux = sr[p].x, uy = sr[p].y;                                   \
            float vx = si[p].x, vy = si[p].y;                                   \
            PLS(ux, vx); PLS(uy, vy);                                           \
            const v2f u = mk2(ux, uy), v = mk2(vx, vy);                         \
            const v2f t1 = pkfma(C, u, nS * v);                                 \
            const v2f t2 = pkfma(C, v,  S * u);                                 \
            float ax = t1.x, ay = t1.y, bx = t2.x, by = t2.y;                   \
            PLS(ax, bx); PLS(ay, by);                                           \
            sr[p] = mk2(ax, ay); si[p] = mk2(bx, by);                           \
        }                                                                       \
    }

#pragma unroll 1
    for (int L = 1; L <= 3; ++L) {
        const float* rl = ry + L * 20;

        RY_PLPAIR(4, PLS32)   // lane bit 5
        RY_PLPAIR(5, PLS16)   // lane bit 4
        RY_LANE_S(6, 8)
        RY_LANE_V(7, 4)
        RY_LANE_S(8, 2)
        RY_LANE_S(9, 1)

        // p-wires j=0,1,2 (p bits 2,1,0): real pair rotations
#pragma unroll
        for (int j = 0; j < 3; ++j) {
            const int pb = 4 >> j;
            const float c = rl[j * 2], s = rl[j * 2 + 1];
            const v2f C = sp2(c), S = sp2(s), nS = sp2(-s);
#pragma unroll
            for (int p0 = 0; p0 < 8; ++p0) {
                if (p0 & pb) continue;
                const int p1 = p0 | pb;
                const v2f a0r = sr[p0], a1r = sr[p1];
                const v2f a0i = si[p0], a1i = si[p1];
                sr[p0] = pkfma(C, a0r, nS * a1r);
                sr[p1] = pkfma(C, a1r,  S * a0r);
                si[p0] = pkfma(C, a0i, nS * a1i);
                si[p1] = pkfma(C, a1i,  S * a0i);
            }
        }

        // e-wire j=3 (intra-v2f): new.x = c*x - s*y ; new.y = s*x + c*y
        {
            const float c = rl[6], s = rl[7];
            const v2f C = sp2(c), Sw = mk2(-s, s);
#pragma unroll
            for (int p = 0; p < 8; ++p) {
                const v2f swr = mk2(sr[p].y, sr[p].x);
                const v2f swi = mk2(si[p].y, si[p].x);
                sr[p] = pkfma(C, sr[p], Sw * swr);
                si[p] = pkfma(C, si[p], Sw * swi);
            }
        }

        // fused diagonal D_{L+1}
        if (L < 3) {
            BUILD_D(L)
#pragma unroll
            for (int p = 0; p < 8; ++p) {
                const v2f tr = pkfma(sr[p], dr[p], -(si[p] * di[p]));
                si[p] = pkfma(sr[p], di[p], si[p] * dr[p]);
                sr[p] = tr;
            }
        }
    }
#undef RY_LANE_S
#undef RY_LANE_V
#undef RY_PLPAIR
#undef BUILD_D

    // ---- <Z_j> ----
    float pe[8], po[8];
#pragma unroll
    for (int p = 0; p < 8; ++p) {
        const v2f pk = pkfma(sr[p], sr[p], si[p] * si[p]);
        pe[p] = pk.x + pk.y;
        po[p] = pk.x - pk.y;
    }
    float tot = 0.f, t0 = 0.f, t1 = 0.f, t2 = 0.f, t3 = 0.f;
#pragma unroll
    for (int p = 0; p < 8; ++p) {
        tot += pe[p];
        t0  += (p & 4) ? -pe[p] : pe[p];   // wire 0 (m bit 3)
        t1  += (p & 2) ? -pe[p] : pe[p];   // wire 1 (m bit 2)
        t2  += (p & 1) ? -pe[p] : pe[p];   // wire 2 (m bit 1)
        t3  += po[p];                      // wire 3 (m bit 0)
    }
    v2f u01 = mk2(t0, t1), u23 = mk2(t2, t3);
    u01 += lxor2<1>(u01);  u23 += lxor2<1>(u23);
    u01 += lxor2<2>(u01);  u23 += lxor2<2>(u23);
    u01 += lxor2<4>(u01);  u23 += lxor2<4>(u23);
    u01 += lxor2<8>(u01);  u23 += lxor2<8>(u23);
    u01 += lxor2<16>(u01); u23 += lxor2<16>(u23);
    u01 += lxor2<32>(u01); u23 += lxor2<32>(u23);

    float Sa = tot, T, D0, D1, D2, D3, D4, D5;
    T = lxor<1>(Sa);  D0 = Sa - T; Sa += T;
    T = lxor<2>(Sa);  D1 = Sa - T; Sa += T;
    T = lxor<4>(Sa);  D2 = Sa - T; Sa += T;
    T = lxor<8>(Sa);  D3 = Sa - T; Sa += T;
    T = lxor<16>(Sa); D4 = Sa - T; Sa += T;
    T = lxor<32>(Sa); D5 = Sa - T;
    D0 += lxor<2>(D0); D0 += lxor<4>(D0); D0 += lxor<8>(D0); D0 += lxor<16>(D0); D0 += lxor<32>(D0);
    D1 += lxor<4>(D1); D1 += lxor<8>(D1); D1 += lxor<16>(D1); D1 += lxor<32>(D1);
    D2 += lxor<8>(D2); D2 += lxor<16>(D2); D2 += lxor<32>(D2);
    D3 += lxor<16>(D3); D3 += lxor<32>(D3);
    D4 += lxor<32>(D4);

    if (lane == 0) {
        float* o = out + b * NQ;
        o[0] = u01.x; o[1] = u01.y; o[2] = u23.x; o[3] = u23.y;
        o[4] = D5;    o[5] = D4;    o[6] = D3;    o[7] = D2;    o[8] = D1;    o[9] = D0;
    }
}

extern "C" void kernel_launch(void* const* d_in, const int* in_sizes, int n_in,
                              void* d_out, int out_size, void* d_ws, size_t ws_size,
                              hipStream_t stream) {
    const float* x  = (const float*)d_in[0];   // [B,10] f32
    const float* w1 = (const float*)d_in[1];   // [3,1,10,3] f32
    const float* w2 = (const float*)d_in[2];   // [1,10,3] f32
    float* out = (float*)d_out;                // [B,10] f32
    const int B = in_sizes[0] / NQ;            // 2048
    qlayer_kernel<<<B, 64, 0, stream>>>(x, w1, w2, out);  // 1 wave per element, no barriers
}

// Round 14
// 17.781 us; speedup vs baseline: 1.0320x; 1.0103x over previous
//
#include <hip/hip_runtime.h>
#include <math.h>

#define NQ 10

typedef float v2f __attribute__((ext_vector_type(2)));

static __device__ __forceinline__ v2f mk2(float a, float b) { v2f r; r.x = a; r.y = b; return r; }
static __device__ __forceinline__ v2f sp2(float a)          { v2f r; r.x = a; r.y = a; return r; }
static __device__ __forceinline__ v2f pkfma(v2f a, v2f b, v2f c) { return __builtin_elementwise_fma(a, b, c); }

// xor-mask lane exchange. Masks 1,2,4,8: DPP (VALU). 16: ds_swizzle. 32: bpermute.
template<int MSK>
static __device__ __forceinline__ float lxor(float v) {
    if constexpr (MSK == 1) {        // quad_perm [1,0,3,2]
        const int s = __float_as_int(v);
        return __int_as_float(__builtin_amdgcn_update_dpp(s, s, 0xB1, 0xF, 0xF, false));
    } else if constexpr (MSK == 2) { // quad_perm [2,3,0,1]
        const int s = __float_as_int(v);
        return __int_as_float(__builtin_amdgcn_update_dpp(s, s, 0x4E, 0xF, 0xF, false));
    } else if constexpr (MSK == 4) {
        // banks 0,2 (bit2=0) need lane+4 -> row_shl:4 ; banks 1,3 (bit2=1) need lane-4 -> row_shr:4
        const int s = __float_as_int(v);
        int t = __builtin_amdgcn_update_dpp(s, s, 0x104, 0xF, 0x5, false);
        t     = __builtin_amdgcn_update_dpp(t, s, 0x114, 0xF, 0xA, false);
        return __int_as_float(t);
    } else if constexpr (MSK == 8) { // row_ror:8 == xor8 within a 16-lane row
        const int s = __float_as_int(v);
        return __int_as_float(__builtin_amdgcn_update_dpp(s, s, 0x128, 0xF, 0xF, false));
    } else if constexpr (MSK == 16) {
        return __int_as_float(__builtin_amdgcn_ds_swizzle(__float_as_int(v), 0x401F));
    } else {
        return __shfl_xor(v, 32, 64);
    }
}
template<int MSK>
static __device__ __forceinline__ v2f lxor2(v2f v) { return mk2(lxor<MSK>(v.x), lxor<MSK>(v.y)); }

// Dual-destination permlane swaps (gfx950, VALU pipe, both operands modified).
#define PLS32(a, b) asm("v_permlane32_swap_b32 %0, %1" : "+v"(a), "+v"(b))
#define PLS16(a, b) asm("v_permlane16_swap_b32 %0, %1" : "+v"(a), "+v"(b))

// One WAVE per batch element (4 per 256-thread block). k = m*64+lane, m = 2p+e.
// Circuit algebraically reduced to:  P0 (real product state = RY0|0..0>)
//   -> D1 -> RY1 -> D2 -> RY2 -> D3 -> RY3 -> |.|^2
// where D_L = CZ * diag(exp(i*ang)), ang from alpha_L[j] = omega_L[j]+x[j]+phi_{L+1}[j].
// Leading RZ(phi0) = global phase (dropped); trailing RZ(omega3)*CZ dropped.
// RY is REAL, so sr and si transform identically -> permlane pair trick for
// masks 32/16; DPP for masks 8/4/2/1; main loop has zero DS ops and no barrier.
// Session note: best-measured variant (R10, 17.75us). TLP x2 (R8), ILP x2 (R12),
// barrier-free desync (R13), DPP fusion (R11) all neutral/worse -> ~17.8us is
// the harness floor for this 2048-wave, 0.08MB-footprint, non-MFMA workload.
__global__ void qlayer_kernel(
    const float* __restrict__ x,    // [B,10]
    const float* __restrict__ w1,   // [3,1,10,3]
    const float* __restrict__ w2,   // [1,10,3]
    float* __restrict__ out)        // [B,10]
{
    __shared__ float ry[4 * 20];   // (c,s)(theta/2) per layer L=0..3, wire j=0..9
    __shared__ float au[3 * 10];   // omega_L[j] + phi_{L+1}[j], L=0..2

    const int t    = threadIdx.x;
    const int lane = t & 63;
    const int w    = t >> 6;
    const int b    = (blockIdx.x << 2) + w;

    if (t < 40) {
        const int L = t / 10, j = t - L * 10;
        const float th = (L < 3) ? w1[L * 30 + j * 3 + 1] : w2[j * 3 + 1];
        float c, s;
        __sincosf(0.5f * th, &s, &c);
        ry[L * 20 + j * 2 + 0] = c;
        ry[L * 20 + j * 2 + 1] = s;
    } else if (t >= 64 && t < 94) {
        const int i = t - 64, L = i / 10, j = i - L * 10;
        au[i] = w1[L * 30 + j * 3 + 2] + ((L < 2) ? w1[(L + 1) * 30 + j * 3] : w2[j * 3]);
    }

    float xv[NQ];
#pragma unroll
    for (int j = 0; j < NQ; ++j) xv[j] = x[b * NQ + j];

    // sign masks (lane bits 0..3; bit set -> +s, clear -> -s)
    int msk[4];
#pragma unroll
    for (int p = 0; p < 4; ++p) msk[p] = ((lane >> p) & 1) ? 0 : 0x80000000;

    // CZ-ring sign per m (k = m<<6 | lane)
    float czm[16];
#pragma unroll
    for (int m = 0; m < 16; ++m) {
        const int k  = (m << 6) | lane;
        const int kr = ((k << 1) | (k >> 9)) & 1023;
        czm[m] = (__popc(k & kr) & 1) ? -1.f : 1.f;
    }

    __syncthreads();   // tables ready (only block barrier)

    // D build: d = cz * exp(i*ang(k)), ang(k) = -SA/2 + sum_{bits set} A[wire]
    v2f dr[8], di[8];
#define BUILD_D(IDX)                                                                   \
    {                                                                                  \
        float A[NQ];                                                                   \
        _Pragma("unroll")                                                              \
        for (int j = 0; j < NQ; ++j) A[j] = au[(IDX) * 10 + j] + xv[j];                \
        float SA = 0.f;                                                                \
        _Pragma("unroll")                                                              \
        for (int j = 0; j < NQ; ++j) SA += A[j];                                       \
        float Tl = 0.f;                                                                \
        _Pragma("unroll")                                                              \
        for (int p = 0; p < 6; ++p) Tl += ((lane >> p) & 1) ? A[9 - p] : 0.f;          \
        const float base = -0.5f * SA + Tl;                                            \
        float fr[4], fi[4];                                                            \
        _Pragma("unroll")                                                              \
        for (int q = 0; q < 4; ++q) __sincosf(A[3 - q], &fi[q], &fr[q]);               \
        float dmr[16], dmi[16];                                                        \
        __sincosf(base, &dmi[0], &dmr[0]);                                             \
        _Pragma("unroll")                                                              \
        for (int m = 1; m < 16; ++m) {                                                 \
            const int q  = (m & 1) ? 0 : (m & 2) ? 1 : (m & 4) ? 2 : 3;                \
            const int pm = m & (m - 1);                                                \
            dmr[m] = dmr[pm] * fr[q] - dmi[pm] * fi[q];                                \
            dmi[m] = dmr[pm] * fi[q] + dmi[pm] * fr[q];                                \
        }                                                                              \
        _Pragma("unroll")                                                              \
        for (int p = 0; p < 8; ++p) {                                                  \
            dr[p] = mk2(dmr[2*p] * czm[2*p], dmr[2*p+1] * czm[2*p+1]);                 \
            di[p] = mk2(dmi[2*p] * czm[2*p], dmi[2*p+1] * czm[2*p+1]);                 \
        }                                                                              \
    }

    // ---- initial product state: RY-block 0 applied to |0..0> ----
    float Plo = 1.f;
#pragma unroll
    for (int p = 0; p < 6; ++p) {       // lane bit p <-> wire 9-p
        const float cc = ry[(9 - p) * 2], ss = ry[(9 - p) * 2 + 1];
        Plo *= ((lane >> p) & 1) ? ss : cc;
    }
    float Pm[16];
    {
        const float c0 = ry[0], s0 = ry[1], c1 = ry[2], s1 = ry[3];
        const float c2 = ry[4], s2 = ry[5], c3 = ry[6], s3 = ry[7];
        float P2[2] = {c3, s3};          // m bit0 = wire 3
        float P4[4], P8[8];
#pragma unroll
        for (int m = 0; m < 4; ++m)  P4[m] = ((m >> 1) ? s2 : c2) * P2[m & 1];
#pragma unroll
        for (int m = 0; m < 8; ++m)  P8[m] = ((m >> 2) ? s1 : c1) * P4[m & 3];
#pragma unroll
        for (int m = 0; m < 16; ++m) Pm[m] = ((m >> 3) ? s0 : c0) * P8[m & 7];
    }

    BUILD_D(0)
    v2f sr[8], si[8];
#pragma unroll
    for (int p = 0; p < 8; ++p) {
        const v2f pv = sp2(Plo) * mk2(Pm[2 * p], Pm[2 * p + 1]);
        sr[p] = pv * dr[p];
        si[p] = pv * di[p];
    }

// DPP lane wires (masks 1,2,4,8): per-lane signed coefficient, in-register partner
#define RY_LANE(J, MSK)                                                         \
    {                                                                           \
        const float c = rl[(J) * 2], s = rl[(J) * 2 + 1];                       \
        const float ssg = __int_as_float(__float_as_int(s) ^ msk[9 - (J)]);     \
        const v2f C = sp2(c), S = sp2(ssg);                                     \
        _Pragma("unroll")                                                       \
        for (int p = 0; p < 8; ++p) {                                           \
            const v2f qr = lxor2<MSK>(sr[p]);                                   \
            const v2f qi = lxor2<MSK>(si[p]);                                   \
            sr[p] = pkfma(C, sr[p], S * qr);                                    \
            si[p] = pkfma(C, si[p], S * qi);                                    \
        }                                                                       \
    }

// permlane pair wires (masks 32,16): swap -> uniform-sign gate -> swap back
#define RY_PLPAIR(J, PLS)                                                       \
    {                                                                           \
        const float c = rl[(J) * 2], s = rl[(J) * 2 + 1];                       \
        const v2f C = sp2(c), S = sp2(s), nS = sp2(-s);                         \
        _Pragma("unroll")                                                       \
        for (int p = 0; p < 8; ++p) {                                           \
            float ux = sr[p].x, uy = sr[p].y;                                   \
            float vx = si[p].x, vy = si[p].y;                                   \
            PLS(ux, vx); PLS(uy, vy);                                           \
            const v2f u = mk2(ux, uy), v = mk2(vx, vy);                         \
            const v2f t1 = pkfma(C, u, nS * v);                                 \
            const v2f t2 = pkfma(C, v,  S * u);                                 \
            float ax = t1.x, ay = t1.y, bx = t2.x, by = t2.y;                   \
            PLS(ax, bx); PLS(ay, by);                                           \
            sr[p] = mk2(ax, ay); si[p] = mk2(bx, by);                           \
        }                                                                       \
    }

#pragma unroll 1
    for (int L = 1; L <= 3; ++L) {
        const float* rl = ry + L * 20;

        RY_PLPAIR(4, PLS32)   // lane bit 5
        RY_PLPAIR(5, PLS16)   // lane bit 4
        RY_LANE(6, 8)
        RY_LANE(7, 4)
        RY_LANE(8, 2)
        RY_LANE(9, 1)

        // p-wires j=0,1,2 (p bits 2,1,0): real pair rotations
#pragma unroll
        for (int j = 0; j < 3; ++j) {
            const int pb = 4 >> j;
            const float c = rl[j * 2], s = rl[j * 2 + 1];
            const v2f C = sp2(c), S = sp2(s), nS = sp2(-s);
#pragma unroll
            for (int p0 = 0; p0 < 8; ++p0) {
                if (p0 & pb) continue;
                const int p1 = p0 | pb;
                const v2f a0r = sr[p0], a1r = sr[p1];
                const v2f a0i = si[p0], a1i = si[p1];
                sr[p0] = pkfma(C, a0r, nS * a1r);
                sr[p1] = pkfma(C, a1r,  S * a0r);
                si[p0] = pkfma(C, a0i, nS * a1i);
                si[p1] = pkfma(C, a1i,  S * a0i);
            }
        }

        // e-wire j=3 (intra-v2f): new.x = c*x - s*y ; new.y = s*x + c*y
        {
            const float c = rl[6], s = rl[7];
            const v2f C = sp2(c), Sw = mk2(-s, s);
#pragma unroll
            for (int p = 0; p < 8; ++p) {
                const v2f swr = mk2(sr[p].y, sr[p].x);
                const v2f swi = mk2(si[p].y, si[p].x);
                sr[p] = pkfma(C, sr[p], Sw * swr);
                si[p] = pkfma(C, si[p], Sw * swi);
            }
        }

        // fused diagonal D_{L+1}
        if (L < 3) {
            BUILD_D(L)
#pragma unroll
            for (int p = 0; p < 8; ++p) {
                const v2f tr = pkfma(sr[p], dr[p], -(si[p] * di[p]));
                si[p] = pkfma(sr[p], di[p], si[p] * dr[p]);
                sr[p] = tr;
            }
        }
    }
#undef RY_LANE
#undef RY_PLPAIR
#undef BUILD_D

    // ---- <Z_j> ----
    float pe[8], po[8];
#pragma unroll
    for (int p = 0; p < 8; ++p) {
        const v2f pk = pkfma(sr[p], sr[p], si[p] * si[p]);
        pe[p] = pk.x + pk.y;
        po[p] = pk.x - pk.y;
    }
    float tot = 0.f, t0 = 0.f, t1 = 0.f, t2 = 0.f, t3 = 0.f;
#pragma unroll
    for (int p = 0; p < 8; ++p) {
        tot += pe[p];
        t0  += (p & 4) ? -pe[p] : pe[p];   // wire 0 (m bit 3)
        t1  += (p & 2) ? -pe[p] : pe[p];   // wire 1 (m bit 2)
        t2  += (p & 1) ? -pe[p] : pe[p];   // wire 2 (m bit 1)
        t3  += po[p];                      // wire 3 (m bit 0)
    }
    v2f u01 = mk2(t0, t1), u23 = mk2(t2, t3);
    u01 += lxor2<1>(u01);  u23 += lxor2<1>(u23);
    u01 += lxor2<2>(u01);  u23 += lxor2<2>(u23);
    u01 += lxor2<4>(u01);  u23 += lxor2<4>(u23);
    u01 += lxor2<8>(u01);  u23 += lxor2<8>(u23);
    u01 += lxor2<16>(u01); u23 += lxor2<16>(u23);
    u01 += lxor2<32>(u01); u23 += lxor2<32>(u23);

    float Sa = tot, T, D0, D1, D2, D3, D4, D5;
    T = lxor<1>(Sa);  D0 = Sa - T; Sa += T;
    T = lxor<2>(Sa);  D1 = Sa - T; Sa += T;
    T = lxor<4>(Sa);  D2 = Sa - T; Sa += T;
    T = lxor<8>(Sa);  D3 = Sa - T; Sa += T;
    T = lxor<16>(Sa); D4 = Sa - T; Sa += T;
    T = lxor<32>(Sa); D5 = Sa - T;
    D0 += lxor<2>(D0); D0 += lxor<4>(D0); D0 += lxor<8>(D0); D0 += lxor<16>(D0); D0 += lxor<32>(D0);
    D1 += lxor<4>(D1); D1 += lxor<8>(D1); D1 += lxor<16>(D1); D1 += lxor<32>(D1);
    D2 += lxor<8>(D2); D2 += lxor<16>(D2); D2 += lxor<32>(D2);
    D3 += lxor<16>(D3); D3 += lxor<32>(D3);
    D4 += lxor<32>(D4);

    if (lane == 0) {
        float* o = out + b * NQ;
        o[0] = u01.x; o[1] = u01.y; o[2] = u23.x; o[3] = u23.y;
        o[4] = D5;    o[5] = D4;    o[6] = D3;    o[7] = D2;    o[8] = D1;    o[9] = D0;
    }
}

extern "C" void kernel_launch(void* const* d_in, const int* in_sizes, int n_in,
                              void* d_out, int out_size, void* d_ws, size_t ws_size,
                              hipStream_t stream) {
    const float* x  = (const float*)d_in[0];   // [B,10] f32
    const float* w1 = (const float*)d_in[1];   // [3,1,10,3] f32
    const float* w2 = (const float*)d_in[2];   // [1,10,3] f32
    float* out = (float*)d_out;                // [B,10] f32
    const int B = in_sizes[0] / NQ;            // 2048
    qlayer_kernel<<<B / 4, 256, 0, stream>>>(x, w1, w2, out);
}